// Round 1
// baseline (1844.238 us; speedup 1.0000x reference)
//
#include <hip/hip_runtime.h>
#include <math.h>

// Problem: B=8, T=64, Cin=64, L=256, F=128, K=5 (SAME pad=2), fp32.
// MFMA per (t,layer): GEMM M=512 (rows r=4f+g), N=2048 (b,l), K=5*Ctot.
// fp32 as bf16x2 (AhBh+AlBh+AhBl, fp32 acc).
// R1: block = m64 x n64 tile, 512 threads = 8 waves (4 K-quarters x 2
// N-halves). Ntile 32->64 halves A-fragment L2 traffic (weight bytes =
// M*K*4 * N/Ntile); the two N-half waves of a K-quarter issue identical
// A loads in near-lockstep -> L1 hits halve effective L2 demand again.
// Grid 256 = 1 block/CU (8 waves/CU, same occupancy as before).
// Staging batched into 2 deep rounds (U=13/17 loads in flight) instead
// of 4 shallow ones to halve the serial global-latency ramp.
// mblk = bx&7 pins weight slices per-XCD (round-robin dispatch).
#define B_SZ 8
#define T_SZ 64
#define CIN 64
#define L_LEN 256
#define F_CH 128
#define K_W 5
#define S_BFL (B_SZ * F_CH * L_LEN)   // 262144

typedef short bf16x8 __attribute__((ext_vector_type(8)));
typedef float f32x4  __attribute__((ext_vector_type(4)));
typedef unsigned int  uint_t;
typedef unsigned short ushort_t;

__device__ __forceinline__ float sigmoid_f(float x) {
    return 1.0f / (1.0f + __expf(-x));
}
__device__ __forceinline__ float tanh_f(float x) {
    float a = fabsf(x);
    float e = __expf(-2.0f * a);
    float t = (1.0f - e) / (1.0f + e);
    return copysignf(t, x);
}
__device__ __forceinline__ ushort_t bf16rne(float f) {
    uint_t u = __float_as_uint(f);
    uint_t r = (u + 0x7FFFu + ((u >> 16) & 1u)) >> 16;
    return (ushort_t)r;
}
// packed word = hi_bf16 | lo_bf16 << 16
__device__ __forceinline__ uint_t pack_f32(float v) {
    ushort_t h = bf16rne(v);
    float hf = __uint_as_float(((uint_t)h) << 16);
    ushort_t l = bf16rne(v - hf);
    return (uint_t)h | (((uint_t)l) << 16);
}

union FragU { uint4 q; bf16x8 v; f32x4 f; float4 f4; };

// ---- Pre-pass: weights -> bf16x2 in A-fragment order ----------------------
// A'[kk=tap*KS+ks][koct][512 rows r=4f+g][8 bf16], hi and lo arrays.
template<int CTOT>
__global__ __launch_bounds__(256)
void convert_w(const float* __restrict__ W, ushort_t* __restrict__ Ahi,
               ushort_t* __restrict__ Alo)
{
    constexpr int KS = CTOT / 32;
    const int idx = blockIdx.x * 256 + threadIdx.x;
    if (idx >= 5 * KS * 4 * 512) return;
    const int r    = idx & 511;
    int rest       = idx >> 9;
    const int koct = rest & 3;  rest >>= 2;
    const int ks   = rest % KS;
    const int tap  = rest / KS;
    const int f = r >> 2, g = r & 3;
    const int row = g * F_CH + f;
    #pragma unroll
    for (int j = 0; j < 8; ++j) {
        int c = ks * 32 + koct * 8 + j;
        float w = W[(row * CTOT + c) * K_W + tap];
        ushort_t h = bf16rne(w);
        ushort_t l = bf16rne(w - __uint_as_float(((uint_t)h) << 16));
        Ahi[idx * 8 + j] = h;
        Alo[idx * 8 + j] = l;
    }
}

__global__ __launch_bounds__(256)
void remap_bias(const float* __restrict__ b0, const float* __restrict__ b1,
                float* __restrict__ br0, float* __restrict__ br1)
{
    int r = blockIdx.x * 256 + threadIdx.x;
    if (r < 512)       br0[r] = b0[(r & 3) * F_CH + (r >> 2)];
    else { r -= 512;   br1[r] = b1[(r & 3) * F_CH + (r >> 2)]; }
}

__global__ __launch_bounds__(256)
void pack_init(const float* __restrict__ h0, const float* __restrict__ h1,
               uint_t* __restrict__ hp0, uint_t* __restrict__ hp1)
{
    int i = blockIdx.x * 256 + threadIdx.x;
    if (i < S_BFL) { hp0[i] = pack_f32(h0[i]); hp1[i] = pack_f32(h1[i]); }
}

// ---- Main step kernel -----------------------------------------------------
// grid = 256: mblk = bx&7 (64 rows, XCD-pinned), nblk = bx>>3 in [0,32):
// b = nblk>>2, l0 = (nblk&3)*64. 8 waves: w&3 = K-quarter, w>>2 = N-half.
template<int C0, int CTOT, bool IN0_F32>
__global__ __launch_bounds__(512, 2)
void step_mfma(const float* __restrict__ in0f, int in0_b_stride,
               const uint_t* __restrict__ in0p,
               const uint_t* __restrict__ hprevp,
               const ushort_t* __restrict__ Ahi, const ushort_t* __restrict__ Alo,
               const float* __restrict__ biasr,
               const float* __restrict__ c_in, float* __restrict__ c_out,
               float* __restrict__ h_out_f32,   // null for layer 0
               uint_t* __restrict__ hp_out)
{
    constexpr int KS = CTOT / 32;
    constexpr int KK = 5 * KS;
    constexpr int STRIDE = CTOT + 4;             // words; %4==0 (b128 align)
    constexpr int LP = 68;                       // 64 cols + 4 halo rows
    constexpr int TILE_W = LP * STRIDE;          // layer1: 17680 w = 70.7 KB
    constexpr int RED_W  = 8 * 8 * 64 * 4;       // reduce scratch: 16384 words
    constexpr int SH_WORDS = (TILE_W > RED_W) ? TILE_W : RED_W;
    __shared__ __align__(16) uint_t sh[SH_WORDS];

    const int tid  = threadIdx.x;
    const int mblk = blockIdx.x & 7;             // XCD-pinned weight slice
    const int nblk = blockIdx.x >> 3;
    const int b    = nblk >> 2;
    const int l0   = (nblk & 3) << 6;

    // ---- Batched staging: rows lp=0..67 (l = l0+lp-2), cols = channels ----
    // Two deep rounds: issue U independent loads (clamped addresses), one
    // wait covers the whole batch of LDS writes (select-zero for halo).
    constexpr int TOT = LP * CTOT;               // 13056 / 17408
    constexpr int U = (TOT + 1023) / 1024;       // 13 / 17 -> 2 rounds
    #pragma unroll
    for (int r = 0; r < 2; ++r) {
        uint_t v[U];
        #pragma unroll
        for (int u = 0; u < U; ++u) {
            const int i = r * (512 * U) + u * 512 + tid;
            if (i < TOT) {
                const int c  = i / LP, lp = i - c * LP;
                const int gl = l0 + lp - 2;
                const int glc = min(max(gl, 0), L_LEN - 1);
                if (IN0_F32) {
                    const float* s = (c < C0) ? (in0f + b * in0_b_stride + c * L_LEN)
                                              : nullptr;
                    v[u] = (c < C0) ? __float_as_uint(s[glc])
                                    : hprevp[(b * F_CH + (c - C0)) * L_LEN + glc];
                } else {
                    v[u] = (c < C0) ? in0p[(b * C0 + c) * L_LEN + glc]
                                    : hprevp[(b * F_CH + (c - C0)) * L_LEN + glc];
                }
            }
        }
        #pragma unroll
        for (int u = 0; u < U; ++u) {
            const int i = r * (512 * U) + u * 512 + tid;
            if (i < TOT) {
                const int c  = i / LP, lp = i - c * LP;
                const int gl = l0 + lp - 2;
                uint_t w = v[u];
                if (IN0_F32 && c < C0) w = pack_f32(__uint_as_float(w));
                if (gl < 0 || gl >= L_LEN) w = 0u;
                sh[lp * STRIDE + c] = w;
            }
        }
    }
    __syncthreads();

    const int w_id = tid >> 6;      // 0..7
    const int q    = w_id & 3;      // K-quarter
    const int nh   = w_id >> 2;     // N-half (columns nh*32 .. nh*32+31)
    const int lane = tid & 63;
    const int l16  = lane & 15, oct = lane >> 4;
    const int mrow = mblk * 64 + l16;
    const int k_lo = (q * KK) / 4, k_hi = ((q + 1) * KK) / 4;

    f32x4 acc[4][2];
    #pragma unroll
    for (int mt = 0; mt < 4; ++mt)
        #pragma unroll
        for (int nf = 0; nf < 2; ++nf) acc[mt][nf] = (f32x4)0.0f;

    const uint4* AH4 = (const uint4*)Ahi;
    const uint4* AL4 = (const uint4*)Alo;
    const uint4* shq = (const uint4*)sh;

    uint4 A0[8], A1[8];
    auto loadA = [&](int kk, uint4* dst) {
        const int base = (kk * 4 + oct) * 512 + mrow;
        #pragma unroll
        for (int mt = 0; mt < 4; ++mt) {
            dst[2 * mt]     = AH4[base + 16 * mt];
            dst[2 * mt + 1] = AL4[base + 16 * mt];
        }
    };
    auto body = [&](int kk, uint4* A) {
        const int tap = kk / KS, ks = kk - tap * KS;
        const int cb  = ks * 8 + oct * 2;
        bf16x8 bh[2], bl[2];
        #pragma unroll
        for (int nf = 0; nf < 2; ++nf) {
            const int row = nh * 32 + nf * 16 + l16 + tap;
            const int r = row * (STRIDE / 4) + cb;
            uint4 p0 = shq[r], p1 = shq[r + 1];
            FragU H, L;
            H.q.x = __builtin_amdgcn_perm(p0.y, p0.x, 0x05040100u);
            H.q.y = __builtin_amdgcn_perm(p0.w, p0.z, 0x05040100u);
            H.q.z = __builtin_amdgcn_perm(p1.y, p1.x, 0x05040100u);
            H.q.w = __builtin_amdgcn_perm(p1.w, p1.z, 0x05040100u);
            L.q.x = __builtin_amdgcn_perm(p0.y, p0.x, 0x07060302u);
            L.q.y = __builtin_amdgcn_perm(p0.w, p0.z, 0x07060302u);
            L.q.z = __builtin_amdgcn_perm(p1.y, p1.x, 0x07060302u);
            L.q.w = __builtin_amdgcn_perm(p1.w, p1.z, 0x07060302u);
            bh[nf] = H.v; bl[nf] = L.v;
        }
        #pragma unroll
        for (int mt = 0; mt < 4; ++mt) {
            FragU TH, TL; TH.q = A[2 * mt]; TL.q = A[2 * mt + 1];
            bf16x8 ah = TH.v, al = TL.v;
            #pragma unroll
            for (int nf = 0; nf < 2; ++nf) {
                acc[mt][nf] = __builtin_amdgcn_mfma_f32_16x16x32_bf16(ah, bh[nf], acc[mt][nf], 0, 0, 0);
                acc[mt][nf] = __builtin_amdgcn_mfma_f32_16x16x32_bf16(al, bh[nf], acc[mt][nf], 0, 0, 0);
                acc[mt][nf] = __builtin_amdgcn_mfma_f32_16x16x32_bf16(ah, bl[nf], acc[mt][nf], 0, 0, 0);
            }
        }
    };

    // Software pipeline: A for kk+1 in flight while MFMAing kk.
    loadA(k_lo, A0);
    for (int kk = k_lo; kk < k_hi; kk += 2) {
        loadA(kk + 1 < k_hi ? kk + 1 : kk, A1);
        body(kk, A0);
        loadA(kk + 2 < k_hi ? kk + 2 : kk, A0);
        if (kk + 1 < k_hi) body(kk + 1, A1);
    }

    // Cross-wave K-reduction through LDS (aliases staging tile).
    __syncthreads();
    float4* scratch = (float4*)sh;
    #pragma unroll
    for (int mt = 0; mt < 4; ++mt)
        #pragma unroll
        for (int nf = 0; nf < 2; ++nf) {
            FragU u; u.f = acc[mt][nf];
            scratch[(w_id * 8 + mt * 2 + nf) * 64 + lane] = u.f4;
        }
    __syncthreads();

    // Wave (q, nh) finalizes mtile q of N-half nh:
    // rows mblk*64+q*16..+15, columns l0+nh*32 .. +31.
    #pragma unroll
    for (int nf = 0; nf < 2; ++nf) {
        float4 s = scratch[((nh * 4 + 0) * 8 + q * 2 + nf) * 64 + lane];
        #pragma unroll
        for (int w = 1; w < 4; ++w) {
            float4 p = scratch[((nh * 4 + w) * 8 + q * 2 + nf) * 64 + lane];
            s.x += p.x; s.y += p.y; s.z += p.z; s.w += p.w;
        }
        const int rbase = mblk * 64 + q * 16 + 4 * oct;     // rows rbase..+3
        const float4 b4 = *(const float4*)(biasr + rbase);
        const int f = rbase >> 2;
        float gi = sigmoid_f(s.x + b4.x);
        float gf = sigmoid_f(s.y + b4.y);
        float go = sigmoid_f(s.z + b4.z);
        float gg = tanh_f(s.w + b4.w);
        const int l   = l0 + nh * 32 + nf * 16 + l16;
        const int idx = (b * F_CH + f) * L_LEN + l;
        float cp = c_in[idx];
        float cn = gf * cp + gi * gg;
        float hn = go * tanh_f(cn);
        c_out[idx] = cn;
        if (h_out_f32) h_out_f32[idx] = hn;
        hp_out[idx] = pack_f32(hn);
    }
}

extern "C" void kernel_launch(void* const* d_in, const int* in_sizes, int n_in,
                              void* d_out, int out_size, void* d_ws, size_t ws_size,
                              hipStream_t stream)
{
    const float* x  = (const float*)d_in[0];  // [B,T,Cin,L]
    const float* W0 = (const float*)d_in[1];  // [512,192,5]
    const float* b0 = (const float*)d_in[2];  // [512]
    const float* W1 = (const float*)d_in[3];  // [512,256,5]
    const float* b1 = (const float*)d_in[4];  // [512]
    const float* h0 = (const float*)d_in[5];  // [B,F,L]
    const float* c0 = (const float*)d_in[6];
    const float* h1 = (const float*)d_in[7];
    const float* c1 = (const float*)d_in[8];
    float* out = (float*)d_out;               // [T,B,F,L]

    const int S = S_BFL;
    float* ws  = (float*)d_ws;
    float* c0w = ws;                          // S floats
    float* c1w = ws + S;                      // S floats
    float* br0 = ws + 2 * S;                  // 512
    float* br1 = br0 + 512;
    uint_t* hp0a = (uint_t*)(ws + 2 * S + 1024);
    uint_t* hp0b = hp0a + S;
    uint_t* hp1a = hp0b + S;
    uint_t* hp1b = hp1a + S;
    ushort_t* Ahi0 = (ushort_t*)(hp1b + S);
    const int N0 = 512 * 192 * 5;             // 491520
    const int N1 = 512 * 256 * 5;             // 655360
    ushort_t* Alo0 = Ahi0 + N0;
    ushort_t* Ahi1 = Alo0 + N0;
    ushort_t* Alo1 = Ahi1 + N1;

    // Pre-pass (graph-safe, every call).
    convert_w<192><<<dim3(240), dim3(256), 0, stream>>>(W0, Ahi0, Alo0);
    convert_w<256><<<dim3(320), dim3(256), 0, stream>>>(W1, Ahi1, Alo1);
    remap_bias<<<dim3(4), dim3(256), 0, stream>>>(b0, b1, br0, br1);
    pack_init<<<dim3((S + 255) / 256), dim3(256), 0, stream>>>(h0, h1, hp0b, hp1b);

    dim3 grid(256), block(512);
    for (int t = 0; t < T_SZ; ++t) {
        uint_t* hp0r = (t & 1) ? hp0a : hp0b;
        uint_t* hp0w = (t & 1) ? hp0b : hp0a;
        uint_t* hp1r = (t & 1) ? hp1a : hp1b;
        uint_t* hp1w = (t & 1) ? hp1b : hp1a;

        step_mfma<CIN, 192, true><<<grid, block, 0, stream>>>(
            x + t * CIN * L_LEN, T_SZ * CIN * L_LEN, (const uint_t*)nullptr,
            hp0r, Ahi0, Alo0, br0,
            t ? (const float*)c0w : c0, c0w,
            (float*)nullptr, hp0w);

        step_mfma<F_CH, 256, false><<<grid, block, 0, stream>>>(
            (const float*)nullptr, 0, hp0w,
            hp1r, Ahi1, Alo1, br1,
            t ? (const float*)c1w : c1, c1w,
            out + (size_t)t * S, hp1w);
    }
}